// Round 23
// baseline (338.629 us; speedup 1.0000x reference)
//
#include <hip/hip_runtime.h>
#include <hip/hip_bf16.h>
#include <math.h>

#define NB 2
#define NPTS 8192
#define KNN 16
#define DOUT 64
#define NKROWS (NPTS*KNN)        // rows per batch = 131072
#define TOTROWS (NB*NPTS*KNN)    // 262144
#define EPSV 1e-5

// Contraction-proof f32 ops (empty-asm value barriers).
__device__ __forceinline__ float mulrn(float a, float b) { float t = a*b; asm("" : "+v"(t)); return t; }
__device__ __forceinline__ float addrn(float a, float b) { float t = a+b; asm("" : "+v"(t)); return t; }

// Reference f32 arithmetic (VERIFIED passing in R13):
//   sq  = fma(z,z, fma(y,y, fl(x*x)))
//   dot = fma(z,z', fma(y,y', fl(x*x')))
//   d   = fl(fma(-2,dot,qsq) + csq)        (cdist tree)
__device__ __forceinline__ float sq_np(float x, float y, float z) {
  return __builtin_fmaf(z, z, __builtin_fmaf(y, y, mulrn(x, x)));
}
__device__ __forceinline__ float dist_np(float qx, float qy, float qz, float qsq,
                                         float cx, float cy, float cz, float csq) {
  const float dot = __builtin_fmaf(qz, cz, __builtin_fmaf(qy, cy, mulrn(qx, cx)));
  return addrn(__builtin_fmaf(-2.0f, dot, qsq), csq);
}

// shfl_down by 1 within a 16-lane DPP row (lanes 0..15 hold the list).
__device__ __forceinline__ float dpp_down1_f(float x) {
  return __int_as_float(__builtin_amdgcn_update_dpp(0, __float_as_int(x), 0x101, 0xF, 0xF, true));
}
__device__ __forceinline__ int dpp_down1_i(int x) {
  return __builtin_amdgcn_update_dpp(0, x, 0x101, 0xF, 0xF, true);
}

// ---------------- K1: brute-force exact KNN, 1 wave per query ----------------
// v5 (R20-verified, 92.5us): DPP list shift + stale-w admission + readlane
// broadcasts. Distributed descending top-16 in lanes 0..15 (lane0 = worst).
// Strict < -> lower index wins on exact ties (stable).
__global__ __launch_bounds__(512, 8) void knn_kernel(const float* __restrict__ xyz,
                                                     int* __restrict__ knn) {
  __shared__ float4 sc[2048];
  const int tid = threadIdx.x;
  const int wv = tid >> 6, lane = tid & 63;
  const int q = blockIdx.x * 8 + wv;          // 2048 blocks * 8 waves = 16384 queries
  const int b = q >> 13, qi = q & (NPTS - 1);
  const float* xb = xyz + (size_t)b * NPTS * 3;
  const float qx = xb[qi*3+0], qy = xb[qi*3+1], qz = xb[qi*3+2];
  const float qsq = sq_np(qx, qy, qz);

  float D = __builtin_inff();
  int   I = 0;
  float w = __builtin_inff();   // 16th-smallest, refreshed once per batch
  const bool is15 = (lane == 15);

  for (int tl = 0; tl < 4; ++tl) {
    if (tl) __syncthreads();
    for (int i = tid; i < 2048; i += 512) {
      const int j = tl*2048 + i;
      const float x = xb[j*3+0], y = xb[j*3+1], z = xb[j*3+2];
      sc[i] = make_float4(x, y, z, sq_np(x, y, z));
    }
    __syncthreads();
    for (int it = 0; it < 32; ++it) {
      const float4 c = sc[it*64 + lane];
      const float d = dist_np(qx, qy, qz, qsq, c.x, c.y, c.z, c.w);
      const int jb = tl*2048 + it*64;
      unsigned long long m = __ballot(d < w);
      while (m) {
        const int src = (int)__builtin_ctzll(m);
        m &= (m - 1ull);
        // SGPR broadcasts (src is wave-uniform)
        const float dc = __int_as_float(__builtin_amdgcn_readlane(__float_as_int(d), src));
        const int   ic = jb + src;
        // unconditional insert: no-op if dc worse than the whole list
        float Dn = dpp_down1_f(D);
        int   In = dpp_down1_i(I);
        Dn = is15 ? -__builtin_inff() : Dn;
        const bool up   = dc < Dn;   // shift: take neighbor's (better) entry
        const bool here = dc < D;    // else insert here
        D = up ? Dn : (here ? dc : D);
        I = up ? In : (here ? ic : I);
      }
      w = __int_as_float(__builtin_amdgcn_readlane(__float_as_int(D), 0));
    }
  }
  if (lane < 16) knn[(size_t)q*KNN + (15 - lane)] = I;  // rank r <-> lane 15-r
}

// ---------------- K2: BN1 stats via spatial-feature moments ----------------
__global__ __launch_bounds__(256) void stats1_kernel(const float* __restrict__ xyz,
                                                     const int* __restrict__ knn,
                                                     float* __restrict__ part1) {
  float acc[65];
#pragma unroll
  for (int i = 0; i < 65; ++i) acc[i] = 0.f;
  const int t0 = blockIdx.x * 256 + threadIdx.x;
  for (int itr = 0; itr < 4; ++itr) {
    const int r = t0 + itr * 65536;
    const int q = r >> 4;
    const int b = q >> 13, qi = q & (NPTS - 1);
    const float* xb = xyz + (size_t)b * NPTS * 3;
    const int j = knn[r];
    const float cx = xb[qi*3], cy = xb[qi*3+1], cz = xb[qi*3+2];
    const float nx = xb[(size_t)j*3], ny = xb[(size_t)j*3+1], nz = xb[(size_t)j*3+2];
    const float rx = nx-cx, ry = ny-cy, rz = nz-cz;
    const float dist = rx*rx + ry*ry + rz*rz;
    const float sf[10] = {cx,cy,cz,nx,ny,nz,rx,ry,rz,dist};
#pragma unroll
    for (int a = 0; a < 10; ++a) acc[a] += sf[a];
    int idx = 10;
#pragma unroll
    for (int a = 0; a < 10; ++a) {
#pragma unroll
      for (int bb = a; bb < 10; ++bb) { acc[idx] += sf[a]*sf[bb]; ++idx; }
    }
  }
  __shared__ float red[4][65];
  const int lane = threadIdx.x & 63, wv = threadIdx.x >> 6;
#pragma unroll
  for (int i = 0; i < 65; ++i) {
    float v = acc[i];
    for (int off = 1; off < 64; off <<= 1) v += __shfl_xor(v, off);
    if (lane == 0) red[wv][i] = v;
  }
  __syncthreads();
  if (threadIdx.x < 65) {
    part1[blockIdx.x*65 + threadIdx.x] =
      red[0][threadIdx.x] + red[1][threadIdx.x] + red[2][threadIdx.x] + red[3][threadIdx.x];
  }
}

__global__ __launch_bounds__(128) void reduce1_kernel(const float* __restrict__ part1,
                                                      const float* __restrict__ W1,
                                                      const float* __restrict__ g1,
                                                      const float* __restrict__ b1,
                                                      float* __restrict__ sb1) {
  __shared__ double tot[65];
  const int t = threadIdx.x;
  if (t < 65) {
    double s = 0.0;
    for (int p = 0; p < 256; ++p) s += (double)part1[p*65 + t];
    tot[t] = s;
  }
  __syncthreads();
  if (t < 64) {
    const double R = (double)TOTROWS;
    double wrow[10];
    for (int j = 0; j < 10; ++j) wrow[j] = (double)W1[t*10 + j];
    double mean = 0.0;
    for (int j = 0; j < 10; ++j) mean += tot[j] * wrow[j];
    mean /= R;
    double msq = 0.0;
    int idx = 10;
    for (int a = 0; a < 10; ++a)
      for (int bb = a; bb < 10; ++bb) {
        const double f = (a == bb) ? 1.0 : 2.0;
        msq += f * wrow[a] * wrow[bb] * tot[idx]; ++idx;
      }
    msq /= R;
    const double var = msq - mean*mean;
    const double inv = 1.0 / sqrt(var + EPSV);
    const double sc = (double)g1[t] * inv;
    sb1[t]      = (float)sc;
    sb1[64 + t] = (float)((double)b1[t] - mean*sc);
  }
}

// Shared row computation: sf -> h1 (BN1+ReLU)
__device__ __forceinline__ void compute_h1(const float* __restrict__ xyz,
                                           const int* __restrict__ knn,
                                           const float* __restrict__ W1,
                                           const float* __restrict__ sb1,
                                           int r, float* h1) {
  const int q = r >> 4;
  const int b = q >> 13, qi = q & (NPTS - 1);
  const float* xb = xyz + (size_t)b * NPTS * 3;
  const int j = knn[r];
  const float cx = xb[qi*3], cy = xb[qi*3+1], cz = xb[qi*3+2];
  const float nx = xb[(size_t)j*3], ny = xb[(size_t)j*3+1], nz = xb[(size_t)j*3+2];
  const float rx = nx-cx, ry = ny-cy, rz = nz-cz;
  const float dist = rx*rx + ry*ry + rz*rz;
  const float sf[10] = {cx,cy,cz,nx,ny,nz,rx,ry,rz,dist};
#pragma unroll
  for (int c = 0; c < 64; ++c) {
    float a = 0.f;
#pragma unroll
    for (int jj = 0; jj < 10; ++jj) a += sf[jj] * W1[c*10 + jj];   // uniform -> s_load
    h1[c] = fmaxf(fmaf(a, sb1[c], sb1[64 + c]), 0.f);
  }
}

// 4-way-split dot product (4 independent FMA chains).
__device__ __forceinline__ float dot64_ilp4(const float* __restrict__ h1,
                                            const float* __restrict__ w) {
  float a0 = 0.f, a1 = 0.f, a2 = 0.f, a3 = 0.f;
#pragma unroll
  for (int jj = 0; jj < 64; jj += 4) {
    a0 += h1[jj+0] * w[jj+0];
    a1 += h1[jj+1] * w[jj+1];
    a2 += h1[jj+2] * w[jj+2];
    a3 += h1[jj+3] * w[jj+3];
  }
  return (a0 + a1) + (a2 + a3);
}

// ---------------- K4: BN2 stats pass — compute h2, accumulate sums, NO write --
__global__ __launch_bounds__(256) void stats2_kernel(const float* __restrict__ xyz,
                                                     const int* __restrict__ knn,
                                                     const float* __restrict__ W1,
                                                     const float* __restrict__ W2,
                                                     const float* __restrict__ sb1,
                                                     float* __restrict__ part2) {
  __shared__ float red[4][128];
  const int tid = threadIdx.x;
  const int r = blockIdx.x*256 + tid;
  float h1[64];
  compute_h1(xyz, knn, W1, sb1, r, h1);
  const int lane = tid & 63, wv = tid >> 6;
#pragma unroll 2
  for (int c = 0; c < 64; ++c) {
    const float a = dot64_ilp4(h1, &W2[c*64]);
    float s = a, s2 = a*a;
    for (int off = 1; off < 64; off <<= 1) { s += __shfl_xor(s, off); s2 += __shfl_xor(s2, off); }
    if (lane == 0) { red[wv][c] = s; red[wv][64 + c] = s2; }
  }
  __syncthreads();
  if (tid < 128) {
    part2[blockIdx.x*128 + tid] = red[0][tid] + red[1][tid] + red[2][tid] + red[3][tid];
  }
}

__global__ __launch_bounds__(1024) void reduce2_kernel(const float* __restrict__ part2,
                                                       const float* __restrict__ g2,
                                                       const float* __restrict__ b2,
                                                       float* __restrict__ sb2) {
  __shared__ double stage[8][128];
  __shared__ double tot[128];
  const int t = threadIdx.x;
  const int c = t & 127, chunk = t >> 7;   // 8 chunks x 128 columns
  double s = 0.0;
  for (int p = chunk*128; p < chunk*128 + 128; ++p) s += (double)part2[p*128 + c];
  stage[chunk][c] = s;
  __syncthreads();
  if (t < 128) {
    double v = 0.0;
    for (int k = 0; k < 8; ++k) v += stage[k][t];
    tot[t] = v;
  }
  __syncthreads();
  if (t < 64) {
    const double R = (double)TOTROWS;
    const double mean = tot[t] / R;
    const double var = tot[64 + t] / R - mean*mean;
    const double inv = 1.0 / sqrt(var + EPSV);
    const double sc = (double)g2[t] * inv;
    sb2[t]      = (float)sc;
    sb2[64 + t] = (float)((double)b2[t] - mean*sc);
  }
}

// ---------------- K6: final pass v2 — channel-split across waves ----------
// 4096 blocks x 256 thr; block owns 64 rows. All 4 waves compute h1 for the
// same 64 rows (redundant, cheap); wave w writes channels [16w,16w+16).
// 4x wave count vs R22 -> 4x in-flight stores + 4x latency hiding.
__global__ __launch_bounds__(256) void final_kernel(const float* __restrict__ xyz,
                                                    const int* __restrict__ knn,
                                                    const float* __restrict__ W1,
                                                    const float* __restrict__ W2,
                                                    const float* __restrict__ sb1,
                                                    const float* __restrict__ sb2,
                                                    float* __restrict__ out) {
  const int tid = threadIdx.x;
  const int lane = tid & 63, wv = tid >> 6;
  const int r = blockIdx.x*64 + lane;
  float h1[64];
  compute_h1(xyz, knn, W1, sb1, r, h1);
  const int b = r >> 17;                 // r / NKROWS
  const int rb = r & (NKROWS - 1);
  float* outb = out + (size_t)b * DOUT * NKROWS;
  const int c0 = wv * 16;
#pragma unroll 2
  for (int ci = 0; ci < 16; ++ci) {
    const int c = c0 + ci;
    const float a = dot64_ilp4(h1, &W2[c*64]);
    outb[(size_t)c * NKROWS + rb] = fmaxf(fmaf(a, sb2[c], sb2[64 + c]), 0.f);
  }
}

extern "C" void kernel_launch(void* const* d_in, const int* in_sizes, int n_in,
                              void* d_out, int out_size, void* d_ws, size_t ws_size,
                              hipStream_t stream) {
  (void)in_sizes; (void)n_in; (void)out_size; (void)ws_size;
  const float* xyz = (const float*)d_in[0];
  // d_in[1] = features : unused by the reference computation
  const float* W1 = (const float*)d_in[2];
  const float* g1 = (const float*)d_in[3];
  const float* b1 = (const float*)d_in[4];
  const float* W2 = (const float*)d_in[5];
  const float* g2 = (const float*)d_in[6];
  const float* b2 = (const float*)d_in[7];
  float* out = (float*)d_out;

  char* ws = (char*)d_ws;
  int*   knn   = (int*)ws;                          // 262144 * 4 B = 1 MiB
  float* part1 = (float*)(ws + 1048576);            // 256*65*4   = 66560 B
  float* part2 = (float*)(ws + 1048576 + 66560);    // 1024*128*4 = 524288 B
  float* sb1   = (float*)(ws + 1048576 + 66560 + 524288);  // 128 f32
  float* sb2   = sb1 + 128;                                 // 128 f32

  hipLaunchKernelGGL(knn_kernel,    dim3(2048), dim3(512),  0, stream, xyz, knn);
  hipLaunchKernelGGL(stats1_kernel, dim3(256),  dim3(256),  0, stream, xyz, knn, part1);
  hipLaunchKernelGGL(reduce1_kernel,dim3(1),    dim3(128),  0, stream, part1, W1, g1, b1, sb1);
  hipLaunchKernelGGL(stats2_kernel, dim3(1024), dim3(256),  0, stream, xyz, knn, W1, W2, sb1, part2);
  hipLaunchKernelGGL(reduce2_kernel,dim3(1),    dim3(1024), 0, stream, part2, g2, b2, sb2);
  hipLaunchKernelGGL(final_kernel,  dim3(4096), dim3(256),  0, stream, xyz, knn, W1, W2, sb1, sb2, out);
}

// Round 24
// 317.686 us; speedup vs baseline: 1.0659x; 1.0659x over previous
//
#include <hip/hip_runtime.h>
#include <hip/hip_bf16.h>
#include <math.h>

#define NB 2
#define NPTS 8192
#define KNN 16
#define DOUT 64
#define NKROWS (NPTS*KNN)        // rows per batch = 131072
#define TOTROWS (NB*NPTS*KNN)    // 262144
#define EPSV 1e-5

// Contraction-proof f32 ops (empty-asm value barriers).
__device__ __forceinline__ float mulrn(float a, float b) { float t = a*b; asm("" : "+v"(t)); return t; }
__device__ __forceinline__ float addrn(float a, float b) { float t = a+b; asm("" : "+v"(t)); return t; }

// Reference f32 arithmetic (VERIFIED passing in R13):
//   sq  = fma(z,z, fma(y,y, fl(x*x)))
//   dot = fma(z,z', fma(y,y', fl(x*x')))
//   d   = fl(fma(-2,dot,qsq) + csq)        (cdist tree)
__device__ __forceinline__ float sq_np(float x, float y, float z) {
  return __builtin_fmaf(z, z, __builtin_fmaf(y, y, mulrn(x, x)));
}
__device__ __forceinline__ float dist_np(float qx, float qy, float qz, float qsq,
                                         float cx, float cy, float cz, float csq) {
  const float dot = __builtin_fmaf(qz, cz, __builtin_fmaf(qy, cy, mulrn(qx, cx)));
  return addrn(__builtin_fmaf(-2.0f, dot, qsq), csq);
}

// shfl_down by 1 within a 16-lane DPP row (lanes 0..15 hold the list).
__device__ __forceinline__ float dpp_down1_f(float x) {
  return __int_as_float(__builtin_amdgcn_update_dpp(0, __float_as_int(x), 0x101, 0xF, 0xF, true));
}
__device__ __forceinline__ int dpp_down1_i(int x) {
  return __builtin_amdgcn_update_dpp(0, x, 0x101, 0xF, 0xF, true);
}

// ---------------- K1: brute-force exact KNN, 1 wave per query ----------------
// v5 (R20-verified, 92.5us): DPP list shift + stale-w admission + readlane
// broadcasts. Distributed descending top-16 in lanes 0..15 (lane0 = worst).
// Strict < -> lower index wins on exact ties (stable).
__global__ __launch_bounds__(512, 8) void knn_kernel(const float* __restrict__ xyz,
                                                     int* __restrict__ knn) {
  __shared__ float4 sc[2048];
  const int tid = threadIdx.x;
  const int wv = tid >> 6, lane = tid & 63;
  const int q = blockIdx.x * 8 + wv;          // 2048 blocks * 8 waves = 16384 queries
  const int b = q >> 13, qi = q & (NPTS - 1);
  const float* xb = xyz + (size_t)b * NPTS * 3;
  const float qx = xb[qi*3+0], qy = xb[qi*3+1], qz = xb[qi*3+2];
  const float qsq = sq_np(qx, qy, qz);

  float D = __builtin_inff();
  int   I = 0;
  float w = __builtin_inff();   // 16th-smallest, refreshed once per batch
  const bool is15 = (lane == 15);

  for (int tl = 0; tl < 4; ++tl) {
    if (tl) __syncthreads();
    for (int i = tid; i < 2048; i += 512) {
      const int j = tl*2048 + i;
      const float x = xb[j*3+0], y = xb[j*3+1], z = xb[j*3+2];
      sc[i] = make_float4(x, y, z, sq_np(x, y, z));
    }
    __syncthreads();
    for (int it = 0; it < 32; ++it) {
      const float4 c = sc[it*64 + lane];
      const float d = dist_np(qx, qy, qz, qsq, c.x, c.y, c.z, c.w);
      const int jb = tl*2048 + it*64;
      unsigned long long m = __ballot(d < w);
      while (m) {
        const int src = (int)__builtin_ctzll(m);
        m &= (m - 1ull);
        // SGPR broadcasts (src is wave-uniform)
        const float dc = __int_as_float(__builtin_amdgcn_readlane(__float_as_int(d), src));
        const int   ic = jb + src;
        // unconditional insert: no-op if dc worse than the whole list
        float Dn = dpp_down1_f(D);
        int   In = dpp_down1_i(I);
        Dn = is15 ? -__builtin_inff() : Dn;
        const bool up   = dc < Dn;   // shift: take neighbor's (better) entry
        const bool here = dc < D;    // else insert here
        D = up ? Dn : (here ? dc : D);
        I = up ? In : (here ? ic : I);
      }
      w = __int_as_float(__builtin_amdgcn_readlane(__float_as_int(D), 0));
    }
  }
  if (lane < 16) knn[(size_t)q*KNN + (15 - lane)] = I;  // rank r <-> lane 15-r
}

// ---------------- K2: BN1 stats via spatial-feature moments ----------------
__global__ __launch_bounds__(256) void stats1_kernel(const float* __restrict__ xyz,
                                                     const int* __restrict__ knn,
                                                     float* __restrict__ part1) {
  float acc[65];
#pragma unroll
  for (int i = 0; i < 65; ++i) acc[i] = 0.f;
  const int t0 = blockIdx.x * 256 + threadIdx.x;
  for (int itr = 0; itr < 4; ++itr) {
    const int r = t0 + itr * 65536;
    const int q = r >> 4;
    const int b = q >> 13, qi = q & (NPTS - 1);
    const float* xb = xyz + (size_t)b * NPTS * 3;
    const int j = knn[r];
    const float cx = xb[qi*3], cy = xb[qi*3+1], cz = xb[qi*3+2];
    const float nx = xb[(size_t)j*3], ny = xb[(size_t)j*3+1], nz = xb[(size_t)j*3+2];
    const float rx = nx-cx, ry = ny-cy, rz = nz-cz;
    const float dist = rx*rx + ry*ry + rz*rz;
    const float sf[10] = {cx,cy,cz,nx,ny,nz,rx,ry,rz,dist};
#pragma unroll
    for (int a = 0; a < 10; ++a) acc[a] += sf[a];
    int idx = 10;
#pragma unroll
    for (int a = 0; a < 10; ++a) {
#pragma unroll
      for (int bb = a; bb < 10; ++bb) { acc[idx] += sf[a]*sf[bb]; ++idx; }
    }
  }
  __shared__ float red[4][65];
  const int lane = threadIdx.x & 63, wv = threadIdx.x >> 6;
#pragma unroll
  for (int i = 0; i < 65; ++i) {
    float v = acc[i];
    for (int off = 1; off < 64; off <<= 1) v += __shfl_xor(v, off);
    if (lane == 0) red[wv][i] = v;
  }
  __syncthreads();
  if (threadIdx.x < 65) {
    part1[blockIdx.x*65 + threadIdx.x] =
      red[0][threadIdx.x] + red[1][threadIdx.x] + red[2][threadIdx.x] + red[3][threadIdx.x];
  }
}

__global__ __launch_bounds__(128) void reduce1_kernel(const float* __restrict__ part1,
                                                      const float* __restrict__ W1,
                                                      const float* __restrict__ g1,
                                                      const float* __restrict__ b1,
                                                      float* __restrict__ sb1) {
  __shared__ double tot[65];
  const int t = threadIdx.x;
  if (t < 65) {
    double s = 0.0;
    for (int p = 0; p < 256; ++p) s += (double)part1[p*65 + t];
    tot[t] = s;
  }
  __syncthreads();
  if (t < 64) {
    const double R = (double)TOTROWS;
    double wrow[10];
    for (int j = 0; j < 10; ++j) wrow[j] = (double)W1[t*10 + j];
    double mean = 0.0;
    for (int j = 0; j < 10; ++j) mean += tot[j] * wrow[j];
    mean /= R;
    double msq = 0.0;
    int idx = 10;
    for (int a = 0; a < 10; ++a)
      for (int bb = a; bb < 10; ++bb) {
        const double f = (a == bb) ? 1.0 : 2.0;
        msq += f * wrow[a] * wrow[bb] * tot[idx]; ++idx;
      }
    msq /= R;
    const double var = msq - mean*mean;
    const double inv = 1.0 / sqrt(var + EPSV);
    const double sc = (double)g1[t] * inv;
    sb1[t]      = (float)sc;
    sb1[64 + t] = (float)((double)b1[t] - mean*sc);
  }
}

// Shared row computation: sf -> h1 (BN1+ReLU)
__device__ __forceinline__ void compute_h1(const float* __restrict__ xyz,
                                           const int* __restrict__ knn,
                                           const float* __restrict__ W1,
                                           const float* __restrict__ sb1,
                                           int r, float* h1) {
  const int q = r >> 4;
  const int b = q >> 13, qi = q & (NPTS - 1);
  const float* xb = xyz + (size_t)b * NPTS * 3;
  const int j = knn[r];
  const float cx = xb[qi*3], cy = xb[qi*3+1], cz = xb[qi*3+2];
  const float nx = xb[(size_t)j*3], ny = xb[(size_t)j*3+1], nz = xb[(size_t)j*3+2];
  const float rx = nx-cx, ry = ny-cy, rz = nz-cz;
  const float dist = rx*rx + ry*ry + rz*rz;
  const float sf[10] = {cx,cy,cz,nx,ny,nz,rx,ry,rz,dist};
#pragma unroll
  for (int c = 0; c < 64; ++c) {
    float a = 0.f;
#pragma unroll
    for (int jj = 0; jj < 10; ++jj) a += sf[jj] * W1[c*10 + jj];   // uniform -> s_load
    h1[c] = fmaxf(fmaf(a, sb1[c], sb1[64 + c]), 0.f);
  }
}

// 4-way-split dot product (4 independent FMA chains).
__device__ __forceinline__ float dot64_ilp4(const float* __restrict__ h1,
                                            const float* __restrict__ w) {
  float a0 = 0.f, a1 = 0.f, a2 = 0.f, a3 = 0.f;
#pragma unroll
  for (int jj = 0; jj < 64; jj += 4) {
    a0 += h1[jj+0] * w[jj+0];
    a1 += h1[jj+1] * w[jj+1];
    a2 += h1[jj+2] * w[jj+2];
    a3 += h1[jj+3] * w[jj+3];
  }
  return (a0 + a1) + (a2 + a3);
}

// ---------------- K4: BN2 stats pass — compute h2, accumulate sums, NO write --
__global__ __launch_bounds__(256) void stats2_kernel(const float* __restrict__ xyz,
                                                     const int* __restrict__ knn,
                                                     const float* __restrict__ W1,
                                                     const float* __restrict__ W2,
                                                     const float* __restrict__ sb1,
                                                     float* __restrict__ part2) {
  __shared__ float red[4][128];
  const int tid = threadIdx.x;
  const int r = blockIdx.x*256 + tid;
  float h1[64];
  compute_h1(xyz, knn, W1, sb1, r, h1);
  const int lane = tid & 63, wv = tid >> 6;
#pragma unroll 2
  for (int c = 0; c < 64; ++c) {
    const float a = dot64_ilp4(h1, &W2[c*64]);
    float s = a, s2 = a*a;
    for (int off = 1; off < 64; off <<= 1) { s += __shfl_xor(s, off); s2 += __shfl_xor(s2, off); }
    if (lane == 0) { red[wv][c] = s; red[wv][64 + c] = s2; }
  }
  __syncthreads();
  if (tid < 128) {
    part2[blockIdx.x*128 + tid] = red[0][tid] + red[1][tid] + red[2][tid] + red[3][tid];
  }
}

__global__ __launch_bounds__(1024) void reduce2_kernel(const float* __restrict__ part2,
                                                       const float* __restrict__ g2,
                                                       const float* __restrict__ b2,
                                                       float* __restrict__ sb2) {
  __shared__ double stage[8][128];
  __shared__ double tot[128];
  const int t = threadIdx.x;
  const int c = t & 127, chunk = t >> 7;   // 8 chunks x 128 columns
  double s = 0.0;
  for (int p = chunk*128; p < chunk*128 + 128; ++p) s += (double)part2[p*128 + c];
  stage[chunk][c] = s;
  __syncthreads();
  if (t < 128) {
    double v = 0.0;
    for (int k = 0; k < 8; ++k) v += stage[k][t];
    tot[t] = v;
  }
  __syncthreads();
  if (t < 64) {
    const double R = (double)TOTROWS;
    const double mean = tot[t] / R;
    const double var = tot[64 + t] / R - mean*mean;
    const double inv = 1.0 / sqrt(var + EPSV);
    const double sc = (double)g2[t] * inv;
    sb2[t]      = (float)sc;
    sb2[64 + t] = (float)((double)b2[t] - mean*sc);
  }
}

// ---------------- K6: final pass v3 — LDS transpose, 1KB contiguous stores --
// 1024 blocks x 256 thr; block owns 256 consecutive rows. Phase 1: each thread
// computes its row's 64 post-BN2 values into LDS [c][256 rows] (conflict-free:
// consecutive tid -> consecutive banks). Phase 2: wave wv copies channels
// [16wv,16wv+16): lane l moves float4 at rows l*4..l*4+3 -> one 1 KB
// contiguous global_store_dwordx4 burst per channel (vs 256 B scattered
// stores before -> DRAM page locality restored).
__global__ __launch_bounds__(256) void final_kernel(const float* __restrict__ xyz,
                                                    const int* __restrict__ knn,
                                                    const float* __restrict__ W1,
                                                    const float* __restrict__ W2,
                                                    const float* __restrict__ sb1,
                                                    const float* __restrict__ sb2,
                                                    float* __restrict__ out) {
  __shared__ float hT[64 * 256];         // [c][row] 64 KiB
  const int tid = threadIdx.x;
  const int r = blockIdx.x*256 + tid;
  float h1[64];
  compute_h1(xyz, knn, W1, sb1, r, h1);
#pragma unroll 2
  for (int c = 0; c < 64; ++c) {
    const float a = dot64_ilp4(h1, &W2[c*64]);
    hT[c*256 + tid] = fmaxf(fmaf(a, sb2[c], sb2[64 + c]), 0.f);
  }
  __syncthreads();
  const int lane = tid & 63, wv = tid >> 6;
  const int rowbase = blockIdx.x * 256;
  const int b = rowbase >> 17;           // / NKROWS
  const int rb0 = rowbase & (NKROWS - 1);
  float* outb = out + (size_t)b * DOUT * NKROWS;
  const float4* hT4 = (const float4*)hT;
#pragma unroll
  for (int ci = 0; ci < 16; ++ci) {
    const int c = wv*16 + ci;
    const float4 v = hT4[c*64 + lane];   // 16B/lane, conflict-free
    *(float4*)(outb + (size_t)c * NKROWS + rb0 + lane*4) = v;
  }
}

extern "C" void kernel_launch(void* const* d_in, const int* in_sizes, int n_in,
                              void* d_out, int out_size, void* d_ws, size_t ws_size,
                              hipStream_t stream) {
  (void)in_sizes; (void)n_in; (void)out_size; (void)ws_size;
  const float* xyz = (const float*)d_in[0];
  // d_in[1] = features : unused by the reference computation
  const float* W1 = (const float*)d_in[2];
  const float* g1 = (const float*)d_in[3];
  const float* b1 = (const float*)d_in[4];
  const float* W2 = (const float*)d_in[5];
  const float* g2 = (const float*)d_in[6];
  const float* b2 = (const float*)d_in[7];
  float* out = (float*)d_out;

  char* ws = (char*)d_ws;
  int*   knn   = (int*)ws;                          // 262144 * 4 B = 1 MiB
  float* part1 = (float*)(ws + 1048576);            // 256*65*4   = 66560 B
  float* part2 = (float*)(ws + 1048576 + 66560);    // 1024*128*4 = 524288 B
  float* sb1   = (float*)(ws + 1048576 + 66560 + 524288);  // 128 f32
  float* sb2   = sb1 + 128;                                 // 128 f32

  hipLaunchKernelGGL(knn_kernel,    dim3(2048), dim3(512),  0, stream, xyz, knn);
  hipLaunchKernelGGL(stats1_kernel, dim3(256),  dim3(256),  0, stream, xyz, knn, part1);
  hipLaunchKernelGGL(reduce1_kernel,dim3(1),    dim3(128),  0, stream, part1, W1, g1, b1, sb1);
  hipLaunchKernelGGL(stats2_kernel, dim3(1024), dim3(256),  0, stream, xyz, knn, W1, W2, sb1, part2);
  hipLaunchKernelGGL(reduce2_kernel,dim3(1),    dim3(1024), 0, stream, part2, g2, b2, sb2);
  hipLaunchKernelGGL(final_kernel,  dim3(1024), dim3(256),  0, stream, xyz, knn, W1, W2, sb1, sb2, out);
}

// Round 25
// 220.627 us; speedup vs baseline: 1.5348x; 1.4399x over previous
//
#include <hip/hip_runtime.h>
#include <hip/hip_bf16.h>
#include <math.h>

#define NB 2
#define NPTS 8192
#define KNN 16
#define DOUT 64
#define NKROWS (NPTS*KNN)        // rows per batch = 131072
#define TOTROWS (NB*NPTS*KNN)    // 262144
#define EPSV 1e-5

// Contraction-proof f32 ops (empty-asm value barriers).
__device__ __forceinline__ float mulrn(float a, float b) { float t = a*b; asm("" : "+v"(t)); return t; }
__device__ __forceinline__ float addrn(float a, float b) { float t = a+b; asm("" : "+v"(t)); return t; }

// Reference f32 arithmetic (VERIFIED passing in R13):
//   sq  = fma(z,z, fma(y,y, fl(x*x)))
//   dot = fma(z,z', fma(y,y', fl(x*x')))
//   d   = fl(fma(-2,dot,qsq) + csq)        (cdist tree)
__device__ __forceinline__ float sq_np(float x, float y, float z) {
  return __builtin_fmaf(z, z, __builtin_fmaf(y, y, mulrn(x, x)));
}
__device__ __forceinline__ float dist_np(float qx, float qy, float qz, float qsq,
                                         float cx, float cy, float cz, float csq) {
  const float dot = __builtin_fmaf(qz, cz, __builtin_fmaf(qy, cy, mulrn(qx, cx)));
  return addrn(__builtin_fmaf(-2.0f, dot, qsq), csq);
}

// shfl_down by 1 within a 16-lane DPP row (lanes 0..15 hold the list).
__device__ __forceinline__ float dpp_down1_f(float x) {
  return __int_as_float(__builtin_amdgcn_update_dpp(0, __float_as_int(x), 0x101, 0xF, 0xF, true));
}
__device__ __forceinline__ int dpp_down1_i(int x) {
  return __builtin_amdgcn_update_dpp(0, x, 0x101, 0xF, 0xF, true);
}

// ---------------- K1: brute-force exact KNN, 1 wave per query ----------------
// v5 (R20-verified, 92.5us): DPP list shift + stale-w admission + readlane
// broadcasts. Distributed descending top-16 in lanes 0..15 (lane0 = worst).
// Strict < -> lower index wins on exact ties (stable).
__global__ __launch_bounds__(512, 8) void knn_kernel(const float* __restrict__ xyz,
                                                     int* __restrict__ knn) {
  __shared__ float4 sc[2048];
  const int tid = threadIdx.x;
  const int wv = tid >> 6, lane = tid & 63;
  const int q = blockIdx.x * 8 + wv;          // 2048 blocks * 8 waves = 16384 queries
  const int b = q >> 13, qi = q & (NPTS - 1);
  const float* xb = xyz + (size_t)b * NPTS * 3;
  const float qx = xb[qi*3+0], qy = xb[qi*3+1], qz = xb[qi*3+2];
  const float qsq = sq_np(qx, qy, qz);

  float D = __builtin_inff();
  int   I = 0;
  float w = __builtin_inff();   // 16th-smallest, refreshed once per batch
  const bool is15 = (lane == 15);

  for (int tl = 0; tl < 4; ++tl) {
    if (tl) __syncthreads();
    for (int i = tid; i < 2048; i += 512) {
      const int j = tl*2048 + i;
      const float x = xb[j*3+0], y = xb[j*3+1], z = xb[j*3+2];
      sc[i] = make_float4(x, y, z, sq_np(x, y, z));
    }
    __syncthreads();
    for (int it = 0; it < 32; ++it) {
      const float4 c = sc[it*64 + lane];
      const float d = dist_np(qx, qy, qz, qsq, c.x, c.y, c.z, c.w);
      const int jb = tl*2048 + it*64;
      unsigned long long m = __ballot(d < w);
      while (m) {
        const int src = (int)__builtin_ctzll(m);
        m &= (m - 1ull);
        // SGPR broadcasts (src is wave-uniform)
        const float dc = __int_as_float(__builtin_amdgcn_readlane(__float_as_int(d), src));
        const int   ic = jb + src;
        // unconditional insert: no-op if dc worse than the whole list
        float Dn = dpp_down1_f(D);
        int   In = dpp_down1_i(I);
        Dn = is15 ? -__builtin_inff() : Dn;
        const bool up   = dc < Dn;   // shift: take neighbor's (better) entry
        const bool here = dc < D;    // else insert here
        D = up ? Dn : (here ? dc : D);
        I = up ? In : (here ? ic : I);
      }
      w = __int_as_float(__builtin_amdgcn_readlane(__float_as_int(D), 0));
    }
  }
  if (lane < 16) knn[(size_t)q*KNN + (15 - lane)] = I;  // rank r <-> lane 15-r
}

// ---------------- K2: BN1 stats via spatial-feature moments ----------------
__global__ __launch_bounds__(256) void stats1_kernel(const float* __restrict__ xyz,
                                                     const int* __restrict__ knn,
                                                     float* __restrict__ part1) {
  float acc[65];
#pragma unroll
  for (int i = 0; i < 65; ++i) acc[i] = 0.f;
  const int t0 = blockIdx.x * 256 + threadIdx.x;
  for (int itr = 0; itr < 4; ++itr) {
    const int r = t0 + itr * 65536;
    const int q = r >> 4;
    const int b = q >> 13, qi = q & (NPTS - 1);
    const float* xb = xyz + (size_t)b * NPTS * 3;
    const int j = knn[r];
    const float cx = xb[qi*3], cy = xb[qi*3+1], cz = xb[qi*3+2];
    const float nx = xb[(size_t)j*3], ny = xb[(size_t)j*3+1], nz = xb[(size_t)j*3+2];
    const float rx = nx-cx, ry = ny-cy, rz = nz-cz;
    const float dist = rx*rx + ry*ry + rz*rz;
    const float sf[10] = {cx,cy,cz,nx,ny,nz,rx,ry,rz,dist};
#pragma unroll
    for (int a = 0; a < 10; ++a) acc[a] += sf[a];
    int idx = 10;
#pragma unroll
    for (int a = 0; a < 10; ++a) {
#pragma unroll
      for (int bb = a; bb < 10; ++bb) { acc[idx] += sf[a]*sf[bb]; ++idx; }
    }
  }
  __shared__ float red[4][65];
  const int lane = threadIdx.x & 63, wv = threadIdx.x >> 6;
#pragma unroll
  for (int i = 0; i < 65; ++i) {
    float v = acc[i];
    for (int off = 1; off < 64; off <<= 1) v += __shfl_xor(v, off);
    if (lane == 0) red[wv][i] = v;
  }
  __syncthreads();
  if (threadIdx.x < 65) {
    part1[blockIdx.x*65 + threadIdx.x] =
      red[0][threadIdx.x] + red[1][threadIdx.x] + red[2][threadIdx.x] + red[3][threadIdx.x];
  }
}

__global__ __launch_bounds__(128) void reduce1_kernel(const float* __restrict__ part1,
                                                      const float* __restrict__ W1,
                                                      const float* __restrict__ g1,
                                                      const float* __restrict__ b1,
                                                      float* __restrict__ sb1) {
  __shared__ double tot[65];
  const int t = threadIdx.x;
  if (t < 65) {
    double s = 0.0;
    for (int p = 0; p < 256; ++p) s += (double)part1[p*65 + t];
    tot[t] = s;
  }
  __syncthreads();
  if (t < 64) {
    const double R = (double)TOTROWS;
    double wrow[10];
    for (int j = 0; j < 10; ++j) wrow[j] = (double)W1[t*10 + j];
    double mean = 0.0;
    for (int j = 0; j < 10; ++j) mean += tot[j] * wrow[j];
    mean /= R;
    double msq = 0.0;
    int idx = 10;
    for (int a = 0; a < 10; ++a)
      for (int bb = a; bb < 10; ++bb) {
        const double f = (a == bb) ? 1.0 : 2.0;
        msq += f * wrow[a] * wrow[bb] * tot[idx]; ++idx;
      }
    msq /= R;
    const double var = msq - mean*mean;
    const double inv = 1.0 / sqrt(var + EPSV);
    const double sc = (double)g1[t] * inv;
    sb1[t]      = (float)sc;
    sb1[64 + t] = (float)((double)b1[t] - mean*sc);
  }
}

// ---------------- K3: sf -> h1 (BN1+ReLU) -> h2 = h1.W2^T ----------------
__global__ __launch_bounds__(256) void main_kernel(const float* __restrict__ xyz,
                                                   const int* __restrict__ knn,
                                                   const float* __restrict__ W1,
                                                   const float* __restrict__ W2,
                                                   const float* __restrict__ sb1,
                                                   float* __restrict__ out,
                                                   float* __restrict__ part2) {
  __shared__ float red[4][128];
  const int tid = threadIdx.x;
  const int r = blockIdx.x*256 + tid;
  const int q = r >> 4;
  const int b = q >> 13, qi = q & (NPTS - 1);
  const float* xb = xyz + (size_t)b * NPTS * 3;
  const int j = knn[r];
  const float cx = xb[qi*3], cy = xb[qi*3+1], cz = xb[qi*3+2];
  const float nx = xb[(size_t)j*3], ny = xb[(size_t)j*3+1], nz = xb[(size_t)j*3+2];
  const float rx = nx-cx, ry = ny-cy, rz = nz-cz;
  const float dist = rx*rx + ry*ry + rz*rz;
  const float sf[10] = {cx,cy,cz,nx,ny,nz,rx,ry,rz,dist};
  float h1[64];
#pragma unroll
  for (int c = 0; c < 64; ++c) {
    float a = 0.f;
#pragma unroll
    for (int jj = 0; jj < 10; ++jj) a += sf[jj] * W1[c*10 + jj];   // uniform -> s_load
    h1[c] = fmaxf(fmaf(a, sb1[c], sb1[64 + c]), 0.f);
  }
  const int lane = tid & 63, wv = tid >> 6;
  const int rb = r & (NKROWS - 1);
  float* outb = out + (size_t)b * DOUT * NKROWS;
#pragma unroll 1
  for (int c = 0; c < 64; ++c) {
    float a = 0.f;
#pragma unroll
    for (int jj = 0; jj < 64; ++jj) a += h1[jj] * W2[c*64 + jj];   // uniform -> s_load
    outb[(size_t)c * NKROWS + rb] = a;
    float s = a, s2 = a*a;
    for (int off = 1; off < 64; off <<= 1) { s += __shfl_xor(s, off); s2 += __shfl_xor(s2, off); }
    if (lane == 0) { red[wv][c] = s; red[wv][64 + c] = s2; }
  }
  __syncthreads();
  if (tid < 128) {
    part2[blockIdx.x*128 + tid] = red[0][tid] + red[1][tid] + red[2][tid] + red[3][tid];
  }
}

__global__ __launch_bounds__(1024) void reduce2_kernel(const float* __restrict__ part2,
                                                       const float* __restrict__ g2,
                                                       const float* __restrict__ b2,
                                                       float* __restrict__ sb2) {
  __shared__ double stage[8][128];
  __shared__ double tot[128];
  const int t = threadIdx.x;
  const int c = t & 127, chunk = t >> 7;   // 8 chunks x 128 columns
  double s = 0.0;
  for (int p = chunk*128; p < chunk*128 + 128; ++p) s += (double)part2[p*128 + c];
  stage[chunk][c] = s;
  __syncthreads();
  if (t < 128) {
    double v = 0.0;
    for (int k = 0; k < 8; ++k) v += stage[k][t];
    tot[t] = v;
  }
  __syncthreads();
  if (t < 64) {
    const double R = (double)TOTROWS;
    const double mean = tot[t] / R;
    const double var = tot[64 + t] / R - mean*mean;
    const double inv = 1.0 / sqrt(var + EPSV);
    const double sc = (double)g2[t] * inv;
    sb2[t]      = (float)sc;
    sb2[64 + t] = (float)((double)b2[t] - mean*sc);
  }
}

// ---------------- K4: in-place BN2 + ReLU on d_out ----------------
__global__ __launch_bounds__(256) void bn2_kernel(float* __restrict__ out,
                                                  const float* __restrict__ sb2) {
  const int n4 = TOTROWS * DOUT / 4;   // 4194304 float4s
  float4* o4 = (float4*)out;
  for (int i = blockIdx.x*256 + threadIdx.x; i < n4; i += gridDim.x * 256) {
    const int c = (i >> 15) & 63;      // 131072 floats = 32768 float4 per (b,c)
    const float sc = sb2[c], bi = sb2[64 + c];
    float4 v = o4[i];
    v.x = fmaxf(fmaf(v.x, sc, bi), 0.f);
    v.y = fmaxf(fmaf(v.y, sc, bi), 0.f);
    v.z = fmaxf(fmaf(v.z, sc, bi), 0.f);
    v.w = fmaxf(fmaf(v.w, sc, bi), 0.f);
    o4[i] = v;
  }
}

extern "C" void kernel_launch(void* const* d_in, const int* in_sizes, int n_in,
                              void* d_out, int out_size, void* d_ws, size_t ws_size,
                              hipStream_t stream) {
  (void)in_sizes; (void)n_in; (void)out_size; (void)ws_size;
  const float* xyz = (const float*)d_in[0];
  // d_in[1] = features : unused by the reference computation
  const float* W1 = (const float*)d_in[2];
  const float* g1 = (const float*)d_in[3];
  const float* b1 = (const float*)d_in[4];
  const float* W2 = (const float*)d_in[5];
  const float* g2 = (const float*)d_in[6];
  const float* b2 = (const float*)d_in[7];
  float* out = (float*)d_out;

  char* ws = (char*)d_ws;
  int*   knn   = (int*)ws;                          // 262144 * 4 B = 1 MiB
  float* part1 = (float*)(ws + 1048576);            // 256*65*4   = 66560 B
  float* part2 = (float*)(ws + 1048576 + 66560);    // 1024*128*4 = 524288 B
  float* sb1   = (float*)(ws + 1048576 + 66560 + 524288);  // 128 f32
  float* sb2   = sb1 + 128;                                 // 128 f32

  hipLaunchKernelGGL(knn_kernel,    dim3(2048), dim3(512),  0, stream, xyz, knn);
  hipLaunchKernelGGL(stats1_kernel, dim3(256),  dim3(256),  0, stream, xyz, knn, part1);
  hipLaunchKernelGGL(reduce1_kernel,dim3(1),    dim3(128),  0, stream, part1, W1, g1, b1, sb1);
  hipLaunchKernelGGL(main_kernel,   dim3(1024), dim3(256),  0, stream, xyz, knn, W1, W2, sb1, out, part2);
  hipLaunchKernelGGL(reduce2_kernel,dim3(1),    dim3(1024), 0, stream, part2, g2, b2, sb2);
  hipLaunchKernelGGL(bn2_kernel,    dim3(2048), dim3(256),  0, stream, out, sb2);
}